// Round 4
// baseline (1525.372 us; speedup 1.0000x reference)
//
#include <hip/hip_runtime.h>
#include <hip/hip_bf16.h>
#include <stdint.h>

// Problem constants
#define B_ 1024
#define T_ 64
#define D_ 256
#define H_ 256
#define G_ 1024   // 4*H

typedef float f32x4 __attribute__((ext_vector_type(4)));
typedef __bf16 bf16x8 __attribute__((ext_vector_type(8)));
typedef unsigned int u32x4 __attribute__((ext_vector_type(4)));

#if __has_builtin(__builtin_amdgcn_rcpf)
#define RCP(x) __builtin_amdgcn_rcpf(x)
#else
#define RCP(x) (1.f / (x))
#endif

__device__ __forceinline__ float bf2f(unsigned int u) {
    unsigned int x = u << 16;
    return __builtin_bit_cast(float, x);
}
__device__ __forceinline__ unsigned short f2bf(float f) {
    __hip_bfloat16 h = __float2bfloat16(f);   // RNE
    return __builtin_bit_cast(unsigned short, h);
}

// ---------------------------------------------------------------------------
// prep_w: W_ih, W_hh f32 -> bf16; bias = b_ih + b_hh; zero the sync flags.
__global__ void prep_w_kernel(const float* __restrict__ Wih, const float* __restrict__ Whh,
                              const float* __restrict__ bih, const float* __restrict__ bhh,
                              unsigned short* __restrict__ wih_bf, unsigned short* __restrict__ whh_bf,
                              float* __restrict__ bias, int* __restrict__ flags) {
    int i = blockIdx.x * 256 + threadIdx.x;   // covers G_*D_ exactly
    wih_bf[i] = f2bf(Wih[i]);
    whh_bf[i] = f2bf(Whh[i]);
    if (i < G_) bias[i] = bih[i] + bhh[i];
    if (i < 128) flags[i] = 0;                // 32 supergroups x 4 quarters
}

// ---------------------------------------------------------------------------
// prep_attn: x_score[b,d] = sum_t x[b,t,d]*w_x[t];  attn[b,:] = softmax_d(x_score)
// (s_hc and b_attn cancel in the softmax). grid 1024 blocks x 256 threads.
__global__ void prep_attn_kernel(const float* __restrict__ x, const float* __restrict__ Wattn,
                                 float* __restrict__ attn) {
    __shared__ float wx[T_];
    __shared__ float red[256];
    int b = blockIdx.x, d = threadIdx.x;
    if (d < T_) wx[d] = Wattn[2 * H_ + d];
    __syncthreads();
    const float* xb = x + (size_t)b * T_ * D_ + d;
    float s = 0.f;
    #pragma unroll
    for (int t = 0; t < T_; ++t) s += xb[t * D_] * wx[t];
    red[d] = s;
    __syncthreads();
    for (int o = 128; o > 0; o >>= 1) {
        if (d < o) red[d] = fmaxf(red[d], red[d + o]);
        __syncthreads();
    }
    float m = red[0];
    __syncthreads();
    float e = __expf(s - m);
    red[d] = e;
    __syncthreads();
    for (int o = 128; o > 0; o >>= 1) {
        if (d < o) red[d] += red[d + o];
        __syncthreads();
    }
    attn[b * D_ + d] = e * (1.f / red[0]);
}

// ---------------------------------------------------------------------------
// winw: w_in = attn (*) x. Writes f32 output 0 ([b][t][d]) and bf16 copy in
// t-major layout [t][b][d] for the GEMM.
__global__ void winw_kernel(const float* __restrict__ x, const float* __restrict__ attn,
                            float* __restrict__ w_out, unsigned short* __restrict__ win_bf) {
    int i4 = blockIdx.x * 256 + threadIdx.x;  // [0, B*T*D/4)
    int e  = i4 * 4;
    int d  = e & 255;
    int bt = e >> 8;            // b*64 + t
    int b  = bt >> 6, t = bt & 63;
    f32x4 xv = *(const f32x4*)(x + e);
    f32x4 av = *(const f32x4*)(attn + b * D_ + d);
    f32x4 w  = xv * av;
    *(f32x4*)(w_out + e) = w;
    ushort4 u;
    u.x = f2bf(w[0]); u.y = f2bf(w[1]); u.z = f2bf(w[2]); u.w = f2bf(w[3]);
    *(ushort4*)(win_bf + ((size_t)(t * B_ + b) * D_ + d)) = u;
}

// ---------------------------------------------------------------------------
// gemmx: pre_gates[m][n] = sum_k w_in[m][k] * W_ih[n][k], m = t*1024+b.
__global__ __launch_bounds__(256, 2) void gemmx_kernel(const unsigned short* __restrict__ A,
                                                       const unsigned short* __restrict__ Bw,
                                                       unsigned short* __restrict__ pre) {
    int bx = blockIdx.x;               // 4096 = 512 x 8
    int bn = bx & 7, bm = bx >> 3;
    int tid = threadIdx.x, lane = tid & 63, w = tid >> 6;
    int wr = w >> 1, wc = w & 1;
    int m0 = bm * 128 + wr * 64, n0 = bn * 128 + wc * 64;
    int lr = lane & 15, lk = (lane >> 4) * 8;

    const unsigned short* Ab[4];
    const unsigned short* Bb[4];
    #pragma unroll
    for (int i = 0; i < 4; ++i) {
        Ab[i] = A  + (size_t)(m0 + i * 16 + lr) * D_ + lk;
        Bb[i] = Bw + (size_t)(n0 + i * 16 + lr) * D_ + lk;
    }
    f32x4 acc[4][4] = {};
    #pragma unroll
    for (int kk = 0; kk < 8; ++kk) {
        bf16x8 a[4], bb[4];
        #pragma unroll
        for (int i = 0; i < 4; ++i) {
            a[i]  = *(const bf16x8*)(Ab[i] + kk * 32);
            bb[i] = *(const bf16x8*)(Bb[i] + kk * 32);
        }
        #pragma unroll
        for (int mi = 0; mi < 4; ++mi)
            #pragma unroll
            for (int ni = 0; ni < 4; ++ni)
                acc[mi][ni] = __builtin_amdgcn_mfma_f32_16x16x32_bf16(a[mi], bb[ni], acc[mi][ni], 0, 0, 0);
    }
    int orow = (lane >> 4) * 4;
    #pragma unroll
    for (int mi = 0; mi < 4; ++mi)
        #pragma unroll
        for (int ni = 0; ni < 4; ++ni)
            #pragma unroll
            for (int q = 0; q < 4; ++q) {
                int m = m0 + mi * 16 + orow + q;
                int n = n0 + ni * 16 + lr;
                pre[(size_t)m * G_ + n] = f2bf(acc[mi][ni][q]);
            }
}

// ---------------------------------------------------------------------------
// seqs v4: 128 blocks = 32 supergroups (32 batch rows) x 4 h-column quarters.
// W_hh slice (256 rows x 256 k = 128 KB bf16, pitch-padded) lives in LDS for
// the whole kernel. Per step the 4 siblings exchange 4 KB h-quarters through
// a DOUBLE-BUFFERED (step parity) hbuf with agent-scope atomics. Flag store
// and flag spin are in SEPARATE reconverging ifs (divergent store/spin in one
// if/else deadlocked round 3). Spin is bounded as a safety valve.
__global__ __launch_bounds__(512, 2) void seqs_kernel(const unsigned short* __restrict__ pre,
                                                      const unsigned short* __restrict__ Whh,
                                                      const float* __restrict__ bias,
                                                      float* __restrict__ enc_out,
                                                      unsigned int* __restrict__ hbuf,
                                                      int* __restrict__ flags) {
    extern __shared__ char smem[];
    unsigned short* W_lds = (unsigned short*)smem;                 // [256][264]
    unsigned short* h_lds = (unsigned short*)(smem + 135168);      // [32][264]

    int tid = threadIdx.x, lane = tid & 63, w = tid >> 6;
    int lr = lane & 15, hi = lane >> 4;
    int bid = blockIdx.x;
    int sg = bid & 31, q4 = bid >> 5;
    int r0 = sg * 32;
    int mt = w & 1, jt = w >> 1;           // m-tile, j-16-range
    int jcol = jt * 16 + lr;               // 0..63 within quarter

    // stage W quarter into LDS: local row ln -> global row (ln>>6)*256 + q4*64 + (ln&63)
    for (int idx = tid; idx < 256 * 32; idx += 512) {
        int row = idx >> 5, ch = idx & 31;
        int R = ((row >> 6) << 8) + (q4 << 6) + (row & 63);
        u32x4 v = *(const u32x4*)(Whh + (size_t)R * 256 + ch * 8);
        *(u32x4*)&W_lds[row * 264 + ch * 8] = v;
    }
    for (int i = tid; i < 32 * 264; i += 512) h_lds[i] = 0;

    float bias_c[4];
    #pragma unroll
    for (int g = 0; g < 4; ++g) bias_c[g] = bias[g * 256 + q4 * 64 + jcol];

    // pre base pointers per q-row
    const unsigned short* pb[4];
    #pragma unroll
    for (int q = 0; q < 4; ++q)
        pb[q] = pre + (size_t)(r0 + mt * 16 + hi * 4 + q) * 1024 + q4 * 64 + jcol;

    unsigned short cur[4][4], nxt[4][4];
    #pragma unroll
    for (int q = 0; q < 4; ++q)
        #pragma unroll
        for (int g = 0; g < 4; ++g)
            cur[q][g] = pb[q][g * 256];          // t = 0

    float cst[4] = {0.f, 0.f, 0.f, 0.f};
    int fl = sg * 4;

    __syncthreads();

    #pragma unroll 1
    for (int t = 0; t < T_; ++t) {
        // prefetch pre for t+1 (hidden under K-loop)
        {
            size_t soff = (size_t)(t < 63 ? t + 1 : 63) * (1024u * 1024u);
            #pragma unroll
            for (int q = 0; q < 4; ++q)
                #pragma unroll
                for (int g = 0; g < 4; ++g)
                    nxt[q][g] = pb[q][soff + g * 256];
        }

        // K-loop: gates_h = h @ W_hh_slice^T, all operands in LDS
        f32x4 acc[4] = {};
        #pragma unroll
        for (int kk = 0; kk < 8; ++kk) {
            bf16x8 a = *(const bf16x8*)&h_lds[(mt * 16 + lr) * 264 + kk * 32 + hi * 8];
            #pragma unroll
            for (int g = 0; g < 4; ++g) {
                bf16x8 b = *(const bf16x8*)&W_lds[(g * 64 + jt * 16 + lr) * 264 + kk * 32 + hi * 8];
                acc[g] = __builtin_amdgcn_mfma_f32_16x16x32_bf16(a, b, acc[g], 0, 0, 0);
            }
        }
        __syncthreads();   // all h_lds reads complete before h(t+1) writes

        // cell update: rows mrow = mt*16 + hi*4 + q, col jcol (all in-register)
        unsigned int par = (unsigned)(t & 1);
        #pragma unroll
        for (int q = 0; q < 4; ++q) {
            int mrow = mt * 16 + hi * 4 + q;
            float gi = acc[0][q] + bf2f((unsigned)cur[q][0]) + bias_c[0];
            float gf = acc[1][q] + bf2f((unsigned)cur[q][1]) + bias_c[1];
            float gg = acc[2][q] + bf2f((unsigned)cur[q][2]) + bias_c[2];
            float go = acc[3][q] + bf2f((unsigned)cur[q][3]) + bias_c[3];
            float si = RCP(1.f + __expf(-gi));
            float sf = RCP(1.f + __expf(-gf));
            float so = RCP(1.f + __expf(-go));
            float tg = 1.f - 2.f * RCP(__expf(2.f * gg) + 1.f);
            float cn = sf * cst[q] + si * tg;
            cst[q] = cn;
            float tc = 1.f - 2.f * RCP(__expf(2.f * cn) + 1.f);
            float h  = so * tc;
            unsigned int hu = (unsigned int)f2bf(h);
            h_lds[mrow * 264 + q4 * 64 + jcol] = (unsigned short)hu;
            enc_out[((size_t)(r0 + mrow) * T_ + t) * H_ + q4 * 64 + jcol] = h;
            if (t < 63) {
                unsigned int ph = (unsigned int)__shfl_xor((int)hu, 1);
                if ((lr & 1) == 0) {
                    unsigned int dw = hu | (ph << 16);
                    __hip_atomic_store(&hbuf[((par * 32 + sg) * 32 + mrow) * 128 + q4 * 32 + (jcol >> 1)],
                                       dw, __ATOMIC_RELAXED, __HIP_MEMORY_SCOPE_AGENT);
                }
            }
        }
        #pragma unroll
        for (int q = 0; q < 4; ++q)
            #pragma unroll
            for (int g = 0; g < 4; ++g)
                cur[q][g] = nxt[q][g];

        __syncthreads();   // all waves' hbuf/h_lds stores done

        if (t < 63) {
            __threadfence();   // agent-scope ordering of hbuf stores before flag

            // publish own flag — SEPARATE if, reconverges before anyone spins
            if (tid == 0)
                __hip_atomic_store(&flags[fl + q4], t + 1, __ATOMIC_RELEASE, __HIP_MEMORY_SCOPE_AGENT);
            // spin for the three siblings (bounded: safety valve against hangs)
            if (tid >= 1 && tid <= 3) {
                int qs = (q4 + tid) & 3;
                int guard = 0;
                while (__hip_atomic_load(&flags[fl + qs], __ATOMIC_ACQUIRE, __HIP_MEMORY_SCOPE_AGENT) <= t) {
                    __builtin_amdgcn_s_sleep(2);
                    if (++guard > (1 << 22)) break;
                }
            }
            __syncthreads();   // siblings' h(t) published

            // pull 3 sibling quarters (4 KB each) into h_lds
            #pragma unroll
            for (int s = 1; s <= 3; ++s) {
                int qs = (q4 + s) & 3;
                #pragma unroll
                for (int p = 0; p < 2; ++p) {
                    int i = tid + p * 512;          // 0..1023 dwords
                    int row = i >> 5, cd = i & 31;
                    unsigned int v = __hip_atomic_load(&hbuf[((par * 32 + sg) * 32 + row) * 128 + qs * 32 + cd],
                                                       __ATOMIC_RELAXED, __HIP_MEMORY_SCOPE_AGENT);
                    *(unsigned int*)&h_lds[row * 264 + qs * 64 + cd * 2] = v;
                }
            }
            __syncthreads();   // h_lds(t+1) fully assembled
        }
    }
}

// ---------------------------------------------------------------------------
extern "C" void kernel_launch(void* const* d_in, const int* in_sizes, int n_in,
                              void* d_out, int out_size, void* d_ws, size_t ws_size,
                              hipStream_t stream) {
    const float* x     = (const float*)d_in[0];
    const float* Wattn = (const float*)d_in[1];
    // d_in[2] = b_attn (cancels in softmax)
    const float* Wih   = (const float*)d_in[3];
    const float* Whh   = (const float*)d_in[4];
    const float* bih   = (const float*)d_in[5];
    const float* bhh   = (const float*)d_in[6];

    char* ws = (char*)d_ws;
    float*          attn   = (float*)(ws);                            // [0,1MB) — dead after winw
    unsigned int*   hbuf   = (unsigned int*)(ws);                     // 1MB (2 parities), reuses attn region
    unsigned short* win_bf = (unsigned short*)(ws + 1048576);         // 32 MB [t][b][d]
    unsigned short* wih_bf = (unsigned short*)(ws + 34603008);        // 512 KB
    unsigned short* whh_bf = (unsigned short*)(ws + 35127296);        // 512 KB
    float*          bias   = (float*)(ws + 35651584);                 // 4 KB
    int*            flags  = (int*)(ws + 35655680);                   // 4 KB (128 ints)
    unsigned short* pre    = (unsigned short*)(ws + 35659776);        // 128 MB [t][b][n]

    float* w_out   = (float*)d_out;                                   // output 0
    float* enc_out = (float*)d_out + (size_t)B_ * T_ * D_;            // output 1

    hipFuncSetAttribute((const void*)seqs_kernel,
                        hipFuncAttributeMaxDynamicSharedMemorySize, 152064);

    prep_w_kernel<<<dim3(1024), dim3(256), 0, stream>>>(Wih, Whh, bih, bhh, wih_bf, whh_bf, bias, flags);
    prep_attn_kernel<<<dim3(1024), dim3(256), 0, stream>>>(x, Wattn, attn);
    winw_kernel<<<dim3(16384), dim3(256), 0, stream>>>(x, attn, w_out, win_bf);
    gemmx_kernel<<<dim3(4096), dim3(256), 0, stream>>>(win_bf, wih_bf, pre);
    seqs_kernel<<<dim3(128), dim3(512), 152064, stream>>>(pre, whh_bf, bias, enc_out, hbuf, flags);
}

// Round 5
// 459.615 us; speedup vs baseline: 3.3188x; 3.3188x over previous
//
#include <hip/hip_runtime.h>
#include <hip/hip_bf16.h>
#include <stdint.h>

// Problem constants
#define B_ 1024
#define T_ 64
#define D_ 256
#define H_ 256
#define G_ 1024   // 4*H

typedef float f32x4 __attribute__((ext_vector_type(4)));
typedef __bf16 bf16x8 __attribute__((ext_vector_type(8)));
typedef unsigned int u32x4 __attribute__((ext_vector_type(4)));

#if __has_builtin(__builtin_amdgcn_rcpf)
#define RCP(x) __builtin_amdgcn_rcpf(x)
#else
#define RCP(x) (1.f / (x))
#endif

__device__ __forceinline__ float bf2f(unsigned int u) {
    unsigned int x = u << 16;
    return __builtin_bit_cast(float, x);
}
__device__ __forceinline__ unsigned short f2bf(float f) {
    __hip_bfloat16 h = __float2bfloat16(f);   // RNE
    return __builtin_bit_cast(unsigned short, h);
}

// ---------------------------------------------------------------------------
// prep_w: W_ih, W_hh f32 -> bf16; bias = b_ih + b_hh.
__global__ void prep_w_kernel(const float* __restrict__ Wih, const float* __restrict__ Whh,
                              const float* __restrict__ bih, const float* __restrict__ bhh,
                              unsigned short* __restrict__ wih_bf, unsigned short* __restrict__ whh_bf,
                              float* __restrict__ bias) {
    int i = blockIdx.x * 256 + threadIdx.x;   // covers G_*D_ exactly
    wih_bf[i] = f2bf(Wih[i]);
    whh_bf[i] = f2bf(Whh[i]);
    if (i < G_) bias[i] = bih[i] + bhh[i];
}

// ---------------------------------------------------------------------------
// prep_attn: attn[b,:] = softmax_d(x_score[b,:]); s_hc and b_attn cancel.
__global__ void prep_attn_kernel(const float* __restrict__ x, const float* __restrict__ Wattn,
                                 float* __restrict__ attn) {
    __shared__ float wx[T_];
    __shared__ float red[256];
    int b = blockIdx.x, d = threadIdx.x;
    if (d < T_) wx[d] = Wattn[2 * H_ + d];
    __syncthreads();
    const float* xb = x + (size_t)b * T_ * D_ + d;
    float s = 0.f;
    #pragma unroll
    for (int t = 0; t < T_; ++t) s += xb[t * D_] * wx[t];
    red[d] = s;
    __syncthreads();
    for (int o = 128; o > 0; o >>= 1) {
        if (d < o) red[d] = fmaxf(red[d], red[d + o]);
        __syncthreads();
    }
    float m = red[0];
    __syncthreads();
    float e = __expf(s - m);
    red[d] = e;
    __syncthreads();
    for (int o = 128; o > 0; o >>= 1) {
        if (d < o) red[d] += red[d + o];
        __syncthreads();
    }
    attn[b * D_ + d] = e * (1.f / red[0]);
}

// ---------------------------------------------------------------------------
// winw: w_in = attn (*) x. f32 out ([b][t][d]) + bf16 copy [t][b][d] for GEMM.
__global__ void winw_kernel(const float* __restrict__ x, const float* __restrict__ attn,
                            float* __restrict__ w_out, unsigned short* __restrict__ win_bf) {
    int i4 = blockIdx.x * 256 + threadIdx.x;  // [0, B*T*D/4)
    int e  = i4 * 4;
    int d  = e & 255;
    int bt = e >> 8;            // b*64 + t
    int b  = bt >> 6, t = bt & 63;
    f32x4 xv = *(const f32x4*)(x + e);
    f32x4 av = *(const f32x4*)(attn + b * D_ + d);
    f32x4 w  = xv * av;
    *(f32x4*)(w_out + e) = w;
    ushort4 u;
    u.x = f2bf(w[0]); u.y = f2bf(w[1]); u.z = f2bf(w[2]); u.w = f2bf(w[3]);
    *(ushort4*)(win_bf + ((size_t)(t * B_ + b) * D_ + d)) = u;
}

// ---------------------------------------------------------------------------
// gemmx: pre_gates[m][n] = sum_k w_in[m][k] * W_ih[n][k], m = t*1024+b.
__global__ __launch_bounds__(256, 2) void gemmx_kernel(const unsigned short* __restrict__ A,
                                                       const unsigned short* __restrict__ Bw,
                                                       unsigned short* __restrict__ pre) {
    int bx = blockIdx.x;               // 4096 = 512 x 8
    int bn = bx & 7, bm = bx >> 3;
    int tid = threadIdx.x, lane = tid & 63, w = tid >> 6;
    int wr = w >> 1, wc = w & 1;
    int m0 = bm * 128 + wr * 64, n0 = bn * 128 + wc * 64;
    int lr = lane & 15, lk = (lane >> 4) * 8;

    const unsigned short* Ab[4];
    const unsigned short* Bb[4];
    #pragma unroll
    for (int i = 0; i < 4; ++i) {
        Ab[i] = A  + (size_t)(m0 + i * 16 + lr) * D_ + lk;
        Bb[i] = Bw + (size_t)(n0 + i * 16 + lr) * D_ + lk;
    }
    f32x4 acc[4][4] = {};
    #pragma unroll
    for (int kk = 0; kk < 8; ++kk) {
        bf16x8 a[4], bb[4];
        #pragma unroll
        for (int i = 0; i < 4; ++i) {
            a[i]  = *(const bf16x8*)(Ab[i] + kk * 32);
            bb[i] = *(const bf16x8*)(Bb[i] + kk * 32);
        }
        #pragma unroll
        for (int mi = 0; mi < 4; ++mi)
            #pragma unroll
            for (int ni = 0; ni < 4; ++ni)
                acc[mi][ni] = __builtin_amdgcn_mfma_f32_16x16x32_bf16(a[mi], bb[ni], acc[mi][ni], 0, 0, 0);
    }
    int orow = (lane >> 4) * 4;
    #pragma unroll
    for (int mi = 0; mi < 4; ++mi)
        #pragma unroll
        for (int ni = 0; ni < 4; ++ni)
            #pragma unroll
            for (int q = 0; q < 4; ++q) {
                int m = m0 + mi * 16 + orow + q;
                int n = n0 + ni * 16 + lr;
                pre[(size_t)m * G_ + n] = f2bf(acc[mi][ni][q]);
            }
}

// ---------------------------------------------------------------------------
// seqs v5 "fortress CU": 64 blocks x 512 threads (8 waves), 16 batch rows per
// block, NO inter-block communication. W_hh tiling per wave (j-span 32 =
// 8 n-tiles of 16x256):
//   - 4 tiles (jt=0, g=0..3) resident in VGPRs (128 regs, loaded once)
//   - 2 tiles (jt=1, g=0..1) resident in LDS (132 KB total)
//   - 2 tiles (jt=1, g=2..3) streamed from XCD-local L2 each step via a
//     32-reg half-K buffer: kk0-3 loaded in the PREVIOUS step (in flight
//     across the raw barrier), kk4-7 reloaded mid-phase-B.
// h double-buffered by parity in LDS -> ONE raw barrier per step (lgkmcnt
// only; vmem stream + enc_out stores never drained). Two K-phases keep live
// accumulators at 4 tiles.
__global__ __launch_bounds__(512, 2) void seqs_kernel(const unsigned short* __restrict__ pre,
                                                      const unsigned short* __restrict__ Whh,
                                                      const float* __restrict__ bias,
                                                      float* __restrict__ enc_out) {
    extern __shared__ char smem[];
    unsigned short* W_lds    = (unsigned short*)smem;                    // [256][264] = 135168 B
    unsigned short* h_par    = (unsigned short*)(smem + 135168);         // [2][16][264] = 16896 B
    float*          bias_lds = (float*)(smem + 135168 + 16896);          // [1024] = 4096 B

    int tid = threadIdx.x, lane = tid & 63, w = tid >> 6;
    int lr = lane & 15, hi = lane >> 4;
    int r0 = blockIdx.x * 16;
    int j0 = w * 32;

    // --- init staging -------------------------------------------------------
    for (int i = tid; i < 1024; i += 512) bias_lds[i] = bias[i];
    for (int i = tid; i < 2 * 16 * 264; i += 512) h_par[i] = 0;
    // LDS W tiles (jt=1, g=0,1): local row = (w*2+g)*16 + lr, n = g*256 + j0 + 16 + lr
    #pragma unroll
    for (int l = 0; l < 2; ++l) {
        int n = l * 256 + j0 + 16 + lr;
        const u32x4* src = (const u32x4*)(Whh + (size_t)n * 256);
        #pragma unroll
        for (int c = 0; c < 8; ++c) {
            int ch = hi + c * 4;
            *(u32x4*)&W_lds[((w * 2 + l) * 16 + lr) * 264 + ch * 8] = src[ch];
        }
    }
    // VGPR W tiles (jt=0, g=0..3), fragment: row lr, k = kk*32 + hi*8
    bf16x8 Wreg[4][8];
    #pragma unroll
    for (int g = 0; g < 4; ++g)
        #pragma unroll
        for (int kk = 0; kk < 8; ++kk)
            Wreg[g][kk] = *(const bf16x8*)(Whh + (size_t)(g * 256 + j0 + lr) * 256 + kk * 32 + hi * 8);
    // stream-tile base pointers (jt=1, g=2,3)
    const unsigned short* Ws[2];
    #pragma unroll
    for (int s = 0; s < 2; ++s)
        Ws[s] = Whh + (size_t)((s + 2) * 256 + j0 + 16 + lr) * 256 + hi * 8;
    // prologue: stream buffer holds kk0-3
    bf16x8 sbuf[2][4];
    #pragma unroll
    for (int s = 0; s < 2; ++s)
        #pragma unroll
        for (int k2 = 0; k2 < 4; ++k2)
            sbuf[s][k2] = *(const bf16x8*)(Ws[s] + k2 * 32);

    const unsigned short* pbase = pre + (size_t)(r0 + hi * 4) * G_ + j0 + lr;  // + q*1024 + g*256 (+16 for B)
    float biasA[4], biasB[4];
    float cA[4] = {}, cB[4] = {};
    __syncthreads();
    #pragma unroll
    for (int g = 0; g < 4; ++g) {
        biasA[g] = bias_lds[g * 256 + j0 + lr];
        biasB[g] = bias_lds[g * 256 + j0 + 16 + lr];
    }

    #pragma unroll 1
    for (int t = 0; t < T_; ++t) {
        // pre-gate loads for THIS step, issued before the K-phases (L3-latency
        // tolerant: first use is ~600+ cy away at phase-A cell update)
        const unsigned short* Ps = pbase + (size_t)t * (1024u * 1024u);
        unsigned short curA[4][4], curB[4][4];
        #pragma unroll
        for (int g = 0; g < 4; ++g)
            #pragma unroll
            for (int q = 0; q < 4; ++q) {
                curA[g][q] = Ps[(size_t)q * 1024 + g * 256];
                curB[g][q] = Ps[(size_t)q * 1024 + g * 256 + 16];
            }

        int p = t & 1;
        const unsigned short* hrd = h_par + p * (16 * 264);
        unsigned short*       hwr = h_par + (p ^ 1) * (16 * 264);

        // ---- Phase A: jt=0, all 4 tiles from VGPRs --------------------------
        f32x4 acc[4] = {};
        #pragma unroll
        for (int kk = 0; kk < 8; ++kk) {
            bf16x8 a = *(const bf16x8*)&hrd[lr * 264 + kk * 32 + hi * 8];
            #pragma unroll
            for (int g = 0; g < 4; ++g)
                acc[g] = __builtin_amdgcn_mfma_f32_16x16x32_bf16(a, Wreg[g][kk], acc[g], 0, 0, 0);
        }
        #pragma unroll
        for (int q = 0; q < 4; ++q) {
            float gi = acc[0][q] + bf2f((unsigned)curA[0][q]) + biasA[0];
            float gf = acc[1][q] + bf2f((unsigned)curA[1][q]) + biasA[1];
            float gg = acc[2][q] + bf2f((unsigned)curA[2][q]) + biasA[2];
            float go = acc[3][q] + bf2f((unsigned)curA[3][q]) + biasA[3];
            float si = RCP(1.f + __expf(-gi));
            float sf = RCP(1.f + __expf(-gf));
            float so = RCP(1.f + __expf(-go));
            float tg = 1.f - 2.f * RCP(__expf(2.f * gg) + 1.f);
            float cn = sf * cA[q] + si * tg;
            cA[q] = cn;
            float tc = 1.f - 2.f * RCP(__expf(2.f * cn) + 1.f);
            float h  = so * tc;
            hwr[(hi * 4 + q) * 264 + j0 + lr] = f2bf(h);
            enc_out[((size_t)(r0 + hi * 4 + q) * T_ + t) * H_ + j0 + lr] = h;
        }

        // ---- Phase B: jt=1: g0,g1 from LDS, g2,g3 streamed ------------------
        f32x4 accB[4] = {};
        #pragma unroll
        for (int kk = 0; kk < 4; ++kk) {
            bf16x8 a  = *(const bf16x8*)&hrd[lr * 264 + kk * 32 + hi * 8];
            bf16x8 b0 = *(const bf16x8*)&W_lds[((w * 2 + 0) * 16 + lr) * 264 + kk * 32 + hi * 8];
            bf16x8 b1 = *(const bf16x8*)&W_lds[((w * 2 + 1) * 16 + lr) * 264 + kk * 32 + hi * 8];
            accB[0] = __builtin_amdgcn_mfma_f32_16x16x32_bf16(a, b0, accB[0], 0, 0, 0);
            accB[1] = __builtin_amdgcn_mfma_f32_16x16x32_bf16(a, b1, accB[1], 0, 0, 0);
            accB[2] = __builtin_amdgcn_mfma_f32_16x16x32_bf16(a, sbuf[0][kk], accB[2], 0, 0, 0);
            accB[3] = __builtin_amdgcn_mfma_f32_16x16x32_bf16(a, sbuf[1][kk], accB[3], 0, 0, 0);
        }
        // kk0-3 consumed: reload buffer with kk4-7 (same step)
        #pragma unroll
        for (int s = 0; s < 2; ++s)
            #pragma unroll
            for (int k2 = 0; k2 < 4; ++k2)
                sbuf[s][k2] = *(const bf16x8*)(Ws[s] + (k2 + 4) * 32);
        #pragma unroll
        for (int kk = 4; kk < 8; ++kk) {
            bf16x8 a  = *(const bf16x8*)&hrd[lr * 264 + kk * 32 + hi * 8];
            bf16x8 b0 = *(const bf16x8*)&W_lds[((w * 2 + 0) * 16 + lr) * 264 + kk * 32 + hi * 8];
            bf16x8 b1 = *(const bf16x8*)&W_lds[((w * 2 + 1) * 16 + lr) * 264 + kk * 32 + hi * 8];
            accB[0] = __builtin_amdgcn_mfma_f32_16x16x32_bf16(a, b0, accB[0], 0, 0, 0);
            accB[1] = __builtin_amdgcn_mfma_f32_16x16x32_bf16(a, b1, accB[1], 0, 0, 0);
            accB[2] = __builtin_amdgcn_mfma_f32_16x16x32_bf16(a, sbuf[0][kk - 4], accB[2], 0, 0, 0);
            accB[3] = __builtin_amdgcn_mfma_f32_16x16x32_bf16(a, sbuf[1][kk - 4], accB[3], 0, 0, 0);
        }
        // reload kk0-3 for NEXT step (in flight across the barrier)
        #pragma unroll
        for (int s = 0; s < 2; ++s)
            #pragma unroll
            for (int k2 = 0; k2 < 4; ++k2)
                sbuf[s][k2] = *(const bf16x8*)(Ws[s] + k2 * 32);

        #pragma unroll
        for (int q = 0; q < 4; ++q) {
            float gi = accB[0][q] + bf2f((unsigned)curB[0][q]) + biasB[0];
            float gf = accB[1][q] + bf2f((unsigned)curB[1][q]) + biasB[1];
            float gg = accB[2][q] + bf2f((unsigned)curB[2][q]) + biasB[2];
            float go = accB[3][q] + bf2f((unsigned)curB[3][q]) + biasB[3];
            float si = RCP(1.f + __expf(-gi));
            float sf = RCP(1.f + __expf(-gf));
            float so = RCP(1.f + __expf(-go));
            float tg = 1.f - 2.f * RCP(__expf(2.f * gg) + 1.f);
            float cn = sf * cB[q] + si * tg;
            cB[q] = cn;
            float tc = 1.f - 2.f * RCP(__expf(2.f * cn) + 1.f);
            float h  = so * tc;
            hwr[(hi * 4 + q) * 264 + j0 + 16 + lr] = f2bf(h);
            enc_out[((size_t)(r0 + hi * 4 + q) * T_ + t) * H_ + j0 + 16 + lr] = h;
        }

        // end-of-step: h(t+1) fully in LDS; only LDS must drain (vmem stays live)
        asm volatile("s_waitcnt lgkmcnt(0)" ::: "memory");
        __builtin_amdgcn_s_barrier();
    }
}

// ---------------------------------------------------------------------------
extern "C" void kernel_launch(void* const* d_in, const int* in_sizes, int n_in,
                              void* d_out, int out_size, void* d_ws, size_t ws_size,
                              hipStream_t stream) {
    const float* x     = (const float*)d_in[0];
    const float* Wattn = (const float*)d_in[1];
    // d_in[2] = b_attn (cancels in softmax)
    const float* Wih   = (const float*)d_in[3];
    const float* Whh   = (const float*)d_in[4];
    const float* bih   = (const float*)d_in[5];
    const float* bhh   = (const float*)d_in[6];

    char* ws = (char*)d_ws;
    float*          attn   = (float*)(ws);                            // 1 MB
    unsigned short* win_bf = (unsigned short*)(ws + 1048576);         // 32 MB [t][b][d]
    unsigned short* wih_bf = (unsigned short*)(ws + 34603008);        // 512 KB
    unsigned short* whh_bf = (unsigned short*)(ws + 35127296);        // 512 KB
    float*          bias   = (float*)(ws + 35651584);                 // 4 KB
    unsigned short* pre    = (unsigned short*)(ws + 35659776);        // 128 MB [t][b][n]

    float* w_out   = (float*)d_out;                                   // output 0
    float* enc_out = (float*)d_out + (size_t)B_ * T_ * D_;            // output 1

    hipFuncSetAttribute((const void*)seqs_kernel,
                        hipFuncAttributeMaxDynamicSharedMemorySize, 156160);

    prep_w_kernel<<<dim3(1024), dim3(256), 0, stream>>>(Wih, Whh, bih, bhh, wih_bf, whh_bf, bias);
    prep_attn_kernel<<<dim3(1024), dim3(256), 0, stream>>>(x, Wattn, attn);
    winw_kernel<<<dim3(16384), dim3(256), 0, stream>>>(x, attn, w_out, win_bf);
    gemmx_kernel<<<dim3(4096), dim3(256), 0, stream>>>(win_bf, wih_bf, pre);
    seqs_kernel<<<dim3(64), dim3(512), 156160, stream>>>(pre, whh_bf, bias, enc_out);
}